// Round 1
// baseline (434.899 us; speedup 1.0000x reference)
//
#include <hip/hip_runtime.h>
#include <math.h>

// ---------------------------------------------------------------------------
// SelfAttention R3: k_qkv rewritten as 256x256 8-phase pipelined GEMM
// (T2 swizzle + T3/T4 counted-vmcnt phases + T5 setprio + T1 XCD swizzle).
// k_attn / k_proj / k_cvt / k_tab unchanged from R2.
// ---------------------------------------------------------------------------

typedef __bf16 bf16_t;
typedef __bf16 bf16x8 __attribute__((ext_vector_type(8)));
typedef __bf16 bf16x4v __attribute__((ext_vector_type(4)));
typedef float  f32x4  __attribute__((ext_vector_type(4)));

#define B_  2
#define T_  2048
#define C_  2048
#define SLICE_ ((size_t)B_ * T_ * C_)  // 8388608

__device__ __forceinline__ void glds16(const void* g, void* l) {
  __builtin_amdgcn_global_load_lds(
      (__attribute__((address_space(1))) void*)(void*)(const_cast<void*>(g)),
      (__attribute__((address_space(3))) void*)(l), 16, 0, 0);
}

// ------------------------- f32 -> bf16 pack --------------------------------
__global__ __launch_bounds__(256) void k_cvt(const float4* __restrict__ in,
                                             bf16x4v* __restrict__ out, int n4) {
  int i = blockIdx.x * 256 + threadIdx.x;
  if (i < n4) {
    float4 v = in[i];
    bf16x4v o;
    o[0] = (bf16_t)v.x; o[1] = (bf16_t)v.y; o[2] = (bf16_t)v.z; o[3] = (bf16_t)v.w;
    out[i] = o;
  }
}

// ------------------------- rope cos/sin table ------------------------------
__global__ __launch_bounds__(256) void k_tab(float2* __restrict__ tab) {
  int i = blockIdx.x * 256 + threadIdx.x;  // 131072
  int t = i >> 6, j = i & 63;
  float thf = (float)pow(10000.0, -(double)(2 * j) / 128.0);
  float angf = (float)t * thf;
  double a = (double)angf;
  tab[i] = make_float2((float)cos(a), (float)sin(a));
}

// ------------------------- QKV GEMM + RoPE epilogue ------------------------
// C[m,n] = sum_k X[m,k] W[n,k]; M=4096, N=6144, K=2048.
// 256x256 tile, BK=64, 512 threads (8 waves, 2Mx4N), 128 KiB LDS (2 tiles),
// 8-phase schedule, counted vmcnt(4) at phases 4/8 only.
//
// LDS layout per tile (A or B): [256 rows][64 cols] bf16, 8x16B chunks/row,
// chunk p of row r holds global chunk (p ^ (r&7))  (same swizzle as R2).
// Half-tile = 128 rows = 16 KiB = 2 glds16 per thread.

struct FragA { bf16x8 v[4][2]; };  // 4 mf x 2 ksub
struct FragB { bf16x8 v[2][2]; };  // 2 nf x 2 ksub

__device__ __forceinline__ void stage_half(const bf16_t* __restrict__ g, int k0,
                                           bf16_t* l, int H, int tid) {
  const int wv = tid >> 6;
#pragma unroll
  for (int s = 0; s < 2; ++s) {
    int ci = s * 512 + tid;          // 0..1023 chunk index within half
    int row = ci >> 3;               // 0..127
    glds16(g + (size_t)(H * 128 + row) * 2048 + k0 + (((ci & 7) ^ (row & 7)) << 3),
           l + H * 8192 + (size_t)(s * 512 + wv * 64) * 8);
  }
}

__device__ __forceinline__ void load_afrags(const bf16_t* buf, int ha, int wm,
                                            int l16, int q4, FragA& fa) {
#pragma unroll
  for (int mf = 0; mf < 4; ++mf) {
    const bf16_t* rp = buf + (ha * 128 + wm * 64 + mf * 16 + l16) * 64;
#pragma unroll
    for (int ks = 0; ks < 2; ++ks)
      fa.v[mf][ks] = *(const bf16x8*)(rp + ((((ks << 2) | q4) ^ (l16 & 7)) << 3));
  }
}

__device__ __forceinline__ void load_bfrags(const bf16_t* buf, int hb, int wn,
                                            int l16, int q4, FragB& fb) {
#pragma unroll
  for (int nf = 0; nf < 2; ++nf) {
    const bf16_t* rp = buf + (hb * 128 + wn * 32 + nf * 16 + l16) * 64;
#pragma unroll
    for (int ks = 0; ks < 2; ++ks)
      fb.v[nf][ks] = *(const bf16x8*)(rp + ((((ks << 2) | q4) ^ (l16 & 7)) << 3));
  }
}

template <int HA, int HB>
__device__ __forceinline__ void phase_mfma(const FragA& fa, const FragB& fb,
                                           f32x4 (&acc)[2][4][2][2]) {
  __builtin_amdgcn_s_setprio(1);
#pragma unroll
  for (int ks = 0; ks < 2; ++ks)
#pragma unroll
    for (int mf = 0; mf < 4; ++mf)
#pragma unroll
      for (int nf = 0; nf < 2; ++nf)
        acc[HA][mf][HB][nf] = __builtin_amdgcn_mfma_f32_16x16x32_bf16(
            fa.v[mf][ks], fb.v[nf][ks], acc[HA][mf][HB][nf], 0, 0, 0);
  __builtin_amdgcn_s_setprio(0);
}

#define BARRIER() asm volatile("s_barrier" ::: "memory")
#define VMCNT4()  asm volatile("s_waitcnt vmcnt(4)" ::: "memory")

__global__ __launch_bounds__(512, 2) void k_qkv(
    const bf16_t* __restrict__ X, const bf16_t* __restrict__ W,
    const float2* __restrict__ tab,
    bf16_t* __restrict__ qb, bf16_t* __restrict__ kb, bf16_t* __restrict__ vtb,
    float* __restrict__ kout, float* __restrict__ vout) {
  const int K = 2048;
  extern __shared__ char smem_raw[];   // 131072 B dynamic
  bf16_t* sm = (bf16_t*)smem_raw;
  bf16_t* AE = sm;              // even K-tile A  (16384 elems)
  bf16_t* AO = sm + 16384;      // odd  K-tile A
  bf16_t* BE = sm + 32768;      // even K-tile B
  bf16_t* BO = sm + 49152;      // odd  K-tile B

  const int tid = threadIdx.x;
  const int lane = tid & 63, wv = tid >> 6;
  const int wm = wv >> 2, wn = wv & 3;          // 2M x 4N waves
  const int q4 = lane >> 4, l16 = lane & 15;

  // XCD-aware bijective swizzle over 384 blocks (384 % 8 == 0)
  const int bid = blockIdx.x;
  const int swz = (bid & 7) * 48 + (bid >> 3);
  const int m0 = (swz & 15) * 256;              // 16 m-blocks
  const int n0 = (swz >> 4) * 256;              // 24 n-blocks

  const bf16_t* Ab = X + (size_t)m0 * K;
  const bf16_t* Wb = W + (size_t)n0 * K;

  f32x4 acc[2][4][2][2];
  {
    f32x4 zero4 = {0.f, 0.f, 0.f, 0.f};
#pragma unroll
    for (int ha = 0; ha < 2; ++ha)
#pragma unroll
      for (int mf = 0; mf < 4; ++mf)
#pragma unroll
        for (int hb = 0; hb < 2; ++hb)
#pragma unroll
          for (int nf = 0; nf < 2; ++nf) acc[ha][mf][hb][nf] = zero4;
  }

  // ---- prologue: tile0 (even) fully; tile1 (odd) halves A-h0, B-h1 -------
  stage_half(Ab, 0, AE, 0, tid);
  stage_half(Wb, 0, BE, 0, tid);
  stage_half(Wb, 0, BE, 1, tid);
  stage_half(Ab, 0, AE, 1, tid);
  stage_half(Ab, 64, AO, 0, tid);
  stage_half(Wb, 64, BO, 1, tid);
  VMCNT4();          // 12 issued -> oldest 8 (= whole even tile) landed
  BARRIER();

  // ---- main loop: 16 iters, 2 K-tiles (BK=64) per iter --------------------
  for (int t = 0; t < 16; ++t) {
    const int kO  = t * 128 + 64;            // odd tile of this iter
    const int kE2 = (t * 128 + 128) & 2047;  // next even tile (wraps: harmless)
    const int kO2 = (t * 128 + 192) & 2047;  // next odd tile

    FragA fa; FragB fb;
    // ph1: quadrant (A0,B0) of even tile; stage odd tile B-h0, A-h1
    load_afrags(AE, 0, wm, l16, q4, fa);
    load_bfrags(BE, 0, wn, l16, q4, fb);
    stage_half(Wb, kO, BO, 0, tid);
    stage_half(Ab, kO, AO, 1, tid);
    BARRIER();
    phase_mfma<0, 0>(fa, fb, acc);
    BARRIER();
    // ph2: (A0,B1); fa reused
    load_bfrags(BE, 1, wn, l16, q4, fb);
    BARRIER();
    phase_mfma<0, 1>(fa, fb, acc);
    BARRIER();
    // ph3: (A1,B1); fb reused; stage next-even A-h0 (slot free after ph1)
    load_afrags(AE, 1, wm, l16, q4, fa);
    stage_half(Ab, kE2, AE, 0, tid);
    BARRIER();
    phase_mfma<1, 1>(fa, fb, acc);
    BARRIER();
    // ph4: (A1,B0); stage next-even B-h1 (free after ph2); counted wait
    load_bfrags(BE, 0, wn, l16, q4, fb);
    stage_half(Wb, kE2, BE, 1, tid);
    VMCNT4();   // guarantees everything issued <= ph1 has landed
    BARRIER();
    phase_mfma<1, 0>(fa, fb, acc);
    BARRIER();
    // ph5: (A0,B0) of odd tile; stage next-even B-h0, A-h1 (free after ph4)
    load_afrags(AO, 0, wm, l16, q4, fa);
    load_bfrags(BO, 0, wn, l16, q4, fb);
    stage_half(Wb, kE2, BE, 0, tid);
    stage_half(Ab, kE2, AE, 1, tid);
    BARRIER();
    phase_mfma<0, 0>(fa, fb, acc);
    BARRIER();
    // ph6: (A0,B1)
    load_bfrags(BO, 1, wn, l16, q4, fb);
    BARRIER();
    phase_mfma<0, 1>(fa, fb, acc);
    BARRIER();
    // ph7: (A1,B1); stage next-odd A-h0 (free after ph5)
    load_afrags(AO, 1, wm, l16, q4, fa);
    stage_half(Ab, kO2, AO, 0, tid);
    BARRIER();
    phase_mfma<1, 1>(fa, fb, acc);
    BARRIER();
    // ph8: (A1,B0); stage next-odd B-h1 (free after ph6); counted wait
    load_bfrags(BO, 0, wn, l16, q4, fb);
    stage_half(Wb, kO2, BO, 1, tid);
    VMCNT4();   // guarantees everything issued <= ph5 has landed
    BARRIER();
    phase_mfma<1, 0>(fa, fb, acc);
    BARRIER();
  }

  __syncthreads();  // drains vmcnt(0) + lgkmcnt(0) + barrier; smem reusable

  // ---- epilogue ------------------------------------------------------------
  const int sec = n0 >> 11;                  // 0=q, 1=k, 2=v (block-uniform)
  const int t0 = m0 & 2047, bb = m0 >> 11, h0 = (n0 & 2047) >> 7;

  if (sec < 2) {
    // two passes of 128 rows through LDS (stride 264), RoPE applied
#pragma unroll
    for (int ha = 0; ha < 2; ++ha) {
      if (ha) __syncthreads();
#pragma unroll
      for (int mf = 0; mf < 4; ++mf)
#pragma unroll
        for (int hb = 0; hb < 2; ++hb)
#pragma unroll
          for (int nf = 0; nf < 2; ++nf)
#pragma unroll
            for (int r = 0; r < 4; ++r) {
              int mlr = wm * 64 + mf * 16 + q4 * 4 + r;        // row in half
              int d2  = hb * 128 + wn * 32 + nf * 16 + l16;    // 0..255
              int d   = d2 & 127;
              float val = acc[ha][mf][hb][nf][r];
              float partner = __shfl_xor(val, 1);
              float2 cs = tab[(t0 + ha * 128 + mlr) * 64 + (d >> 1)];
              float rv = (d & 1) ? (val * cs.x + partner * cs.y)
                                 : (val * cs.x - partner * cs.y);
              if (sec == 0) rv *= 0.08838834764831845f;  // fold 1/sqrt(hd)
              else kout[(size_t)(m0 + ha * 128 + mlr) * 2048 +
                        (h0 + hb) * 128 + d] = val;
              sm[mlr * 264 + d2] = (bf16_t)rv;
            }
      __syncthreads();
      bf16_t* dst = (sec == 0 ? qb : kb);
#pragma unroll
      for (int i = 0; i < 8; ++i) {
        int ci = i * 512 + tid;                 // 0..4095
        int mlr = ci >> 5, cc = (ci & 31) * 8;
        int hs = cc >> 7, d = cc & 127;
        *(bf16x8*)(dst +
                   ((size_t)(bb * 16 + h0 + hs) * 2048 + t0 + ha * 128 + mlr) * 128 +
                   d) = *(const bf16x8*)&sm[mlr * 264 + cc];
      }
    }
  } else {
    // v: direct f32 out + 128d x 256t transpose via LDS per head
#pragma unroll
    for (int hb = 0; hb < 2; ++hb) {
      if (hb) __syncthreads();
#pragma unroll
      for (int ha = 0; ha < 2; ++ha)
#pragma unroll
        for (int mf = 0; mf < 4; ++mf)
#pragma unroll
          for (int nf = 0; nf < 2; ++nf)
#pragma unroll
            for (int r = 0; r < 4; ++r) {
              int ml = ha * 128 + wm * 64 + mf * 16 + q4 * 4 + r;  // 0..255
              int d2 = hb * 128 + wn * 32 + nf * 16 + l16;
              int d  = d2 & 127;
              float val = acc[ha][mf][hb][nf][r];
              vout[((size_t)(bb * 16 + h0 + hb) * 2048 + t0 + ml) * 128 + d] = val;
              sm[d * 264 + ml] = (bf16_t)val;   // transpose in LDS
            }
      __syncthreads();
#pragma unroll
      for (int i = 0; i < 8; ++i) {
        int ci = i * 512 + tid;                 // 0..4095
        int dr = ci >> 5, cc = (ci & 31) * 8;
        *(bf16x8*)(vtb +
                   ((size_t)((bb * 16 + h0 + hb) * 128 + dr)) * 2048 + t0 + cc) =
            *(const bf16x8*)&sm[dr * 264 + cc];
      }
    }
  }
}

// ------------------------- flash attention ---------------------------------
// block = (b,h) x 128 queries, 4 waves x 32 queries. KT=64. Q in registers.
// No-max softmax: O_unnorm += exp(s) V; l += sum exp(s); normalize at end.
__global__ __launch_bounds__(256, 2) void k_attn(
    const bf16_t* __restrict__ qb, const bf16_t* __restrict__ kb,
    const bf16_t* __restrict__ vtb, bf16_t* __restrict__ ob) {
  __shared__ alignas(16) bf16_t Ps[128 * 80];   // P tile, stride 80
  __shared__ alignas(16) bf16_t Ks[64 * 128];   // swizzled
  __shared__ alignas(16) bf16_t Vts[128 * 64];  // swizzled, [d][key]

  const int tid = threadIdx.x;
  const int lane = tid & 63, wv = tid >> 6;
  const int q4 = lane >> 4, l16 = lane & 15;
  const int bh = blockIdx.x >> 4;
  const int q0 = (blockIdx.x & 15) * 128;

  const bf16_t* Qg = qb + (size_t)bh * T_ * 128 + (size_t)q0 * 128;
  const bf16_t* Kg = kb + (size_t)bh * T_ * 128;
  const bf16_t* Vg = vtb + (size_t)bh * 128 * T_;

  // Q frags straight from global (one-time, pre-scaled by 1/sqrt(hd))
  bf16x8 qa[2][4];
#pragma unroll
  for (int mf = 0; mf < 2; ++mf)
#pragma unroll
    for (int kf = 0; kf < 4; ++kf)
      qa[mf][kf] = *(const bf16x8*)(Qg + (size_t)(wv * 32 + mf * 16 + l16) * 128 +
                                    kf * 32 + q4 * 8);

  f32x4 zero4 = {0.f, 0.f, 0.f, 0.f};
  float lrow[2][4];
  f32x4 oacc[2][8];
#pragma unroll
  for (int mf = 0; mf < 2; ++mf) {
#pragma unroll
    for (int r = 0; r < 4; ++r) lrow[mf][r] = 0.f;
#pragma unroll
    for (int nf = 0; nf < 8; ++nf) oacc[mf][nf] = zero4;
  }

  for (int key0 = 0; key0 < T_; key0 += 64) {
    __syncthreads();
#pragma unroll
    for (int i = 0; i < 4; ++i) {  // Ks: 64 rows x 16 chunks, swizzled
      int ci = i * 256 + tid;
      glds16(Kg + (size_t)(key0 + (ci >> 4)) * 128 +
                 (((ci & 15) ^ ((ci >> 4) & 7)) << 3),
             &Ks[(i * 256 + wv * 64) * 8]);
    }
#pragma unroll
    for (int i = 0; i < 4; ++i) {  // Vts: 128 rows(d) x 8 chunks, swizzled
      int ci = i * 256 + tid;
      glds16(Vg + (size_t)(ci >> 3) * T_ + key0 +
                 (((ci & 7) ^ ((ci >> 3) & 7)) << 3),
             &Vts[(i * 256 + wv * 64) * 8]);
    }
    __syncthreads();

    // S = Q K^T (pre-scaled)
    f32x4 sacc[2][4];
#pragma unroll
    for (int mf = 0; mf < 2; ++mf)
#pragma unroll
      for (int nf = 0; nf < 4; ++nf) sacc[mf][nf] = zero4;
#pragma unroll
    for (int kf = 0; kf < 4; ++kf) {
      bf16x8 bfrag[4];
#pragma unroll
      for (int nf = 0; nf < 4; ++nf)
        bfrag[nf] = *(const bf16x8*)&Ks[(nf * 16 + l16) * 128 +
                                        ((((kf << 2) | q4) ^ (l16 & 7)) << 3)];
#pragma unroll
      for (int mf = 0; mf < 2; ++mf)
#pragma unroll
        for (int nf = 0; nf < 4; ++nf)
          sacc[mf][nf] = __builtin_amdgcn_mfma_f32_16x16x32_bf16(
              qa[mf][kf], bfrag[nf], sacc[mf][nf], 0, 0, 0);
    }

    // exp + P to LDS; per-lane partial row sums (reduced after key loop)
#pragma unroll
    for (int mf = 0; mf < 2; ++mf) {
#pragma unroll
      for (int r = 0; r < 4; ++r) {
        float p0 = __expf(sacc[mf][0][r]);
        float p1 = __expf(sacc[mf][1][r]);
        float p2 = __expf(sacc[mf][2][r]);
        float p3 = __expf(sacc[mf][3][r]);
        int prow = wv * 32 + mf * 16 + q4 * 4 + r;
        Ps[prow * 80 + 0 + l16]  = (bf16_t)p0;
        Ps[prow * 80 + 16 + l16] = (bf16_t)p1;
        Ps[prow * 80 + 32 + l16] = (bf16_t)p2;
        Ps[prow * 80 + 48 + l16] = (bf16_t)p3;
        lrow[mf][r] += (p0 + p1) + (p2 + p3);
      }
    }

    // O += P V
#pragma unroll
    for (int kf2 = 0; kf2 < 2; ++kf2) {
      bf16x8 pa[2], vb[8];
#pragma unroll
      for (int mf = 0; mf < 2; ++mf)
        pa[mf] = *(const bf16x8*)&Ps[(wv * 32 + mf * 16 + l16) * 80 +
                                     kf2 * 32 + q4 * 8];
#pragma unroll
      for (int nf = 0; nf < 8; ++nf)
        vb[nf] = *(const bf16x8*)&Vts[(nf * 16 + l16) * 64 +
                                      ((((kf2 << 2) | q4) ^ (l16 & 7)) << 3)];
#pragma unroll
      for (int mf = 0; mf < 2; ++mf)
#pragma unroll
        for (int nf = 0; nf < 8; ++nf)
          oacc[mf][nf] = __builtin_amdgcn_mfma_f32_16x16x32_bf16(
              pa[mf], vb[nf], oacc[mf][nf], 0, 0, 0);
    }
  }

  // reduce l across the 16-lane row group, then normalize + store
  const int b = bh >> 4, h = bh & 15;
#pragma unroll
  for (int mf = 0; mf < 2; ++mf) {
#pragma unroll
    for (int r = 0; r < 4; ++r) {
      float l = lrow[mf][r];
      l += __shfl_xor(l, 1);
      l += __shfl_xor(l, 2);
      l += __shfl_xor(l, 4);
      l += __shfl_xor(l, 8);
      float inv = 1.f / l;
      int t = q0 + wv * 32 + mf * 16 + q4 * 4 + r;
      size_t base = ((size_t)b * 2048 + t) * 2048 + h * 128;
#pragma unroll
      for (int nf = 0; nf < 8; ++nf)
        ob[base + nf * 16 + l16] = (bf16_t)(oacc[mf][nf][r] * inv);
    }
  }
}

// ------------------------- projection GEMM ---------------------------------
__global__ __launch_bounds__(256, 2) void k_proj(
    const bf16_t* __restrict__ O, const bf16_t* __restrict__ Wp,
    float* __restrict__ Y) {
  const int K = 2048;
  __shared__ alignas(16) bf16_t As[128 * 64];
  __shared__ alignas(16) bf16_t Bs[128 * 64];
  const int tid = threadIdx.x;
  const int lane = tid & 63, wv = tid >> 6;
  const int wm = wv >> 1, wn = wv & 1;
  const int q4 = lane >> 4, l16 = lane & 15;
  const int m0 = blockIdx.x * 128, n0 = blockIdx.y * 128;

  const bf16_t* Ab = O + (size_t)m0 * K;
  const bf16_t* Wb = Wp + (size_t)n0 * K;

  f32x4 zero4 = {0.f, 0.f, 0.f, 0.f};
  f32x4 acc[4][4];
#pragma unroll
  for (int i = 0; i < 4; ++i)
#pragma unroll
    for (int j = 0; j < 4; ++j) acc[i][j] = zero4;

  for (int k0 = 0; k0 < K; k0 += 64) {
    __syncthreads();
#pragma unroll
    for (int i = 0; i < 4; ++i) {
      int ci = i * 256 + tid;
      glds16(Ab + (size_t)(ci >> 3) * K + k0 + (((ci & 7) ^ ((ci >> 3) & 7)) << 3),
             &As[(i * 256 + wv * 64) * 8]);
    }
#pragma unroll
    for (int i = 0; i < 4; ++i) {
      int ci = i * 256 + tid;
      glds16(Wb + (size_t)(ci >> 3) * K + k0 + (((ci & 7) ^ ((ci >> 3) & 7)) << 3),
             &Bs[(i * 256 + wv * 64) * 8]);
    }
    __syncthreads();
#pragma unroll
    for (int kk = 0; kk < 2; ++kk) {
      bf16x8 afrag[4], bfrag[4];
#pragma unroll
      for (int mf = 0; mf < 4; ++mf)
        afrag[mf] = *(const bf16x8*)&As[(wm * 64 + mf * 16 + l16) * 64 +
                                        ((((kk << 2) | q4) ^ (l16 & 7)) << 3)];
#pragma unroll
      for (int nf = 0; nf < 4; ++nf)
        bfrag[nf] = *(const bf16x8*)&Bs[(wn * 64 + nf * 16 + l16) * 64 +
                                        ((((kk << 2) | q4) ^ (l16 & 7)) << 3)];
#pragma unroll
      for (int mf = 0; mf < 4; ++mf)
#pragma unroll
        for (int nf = 0; nf < 4; ++nf)
          acc[mf][nf] = __builtin_amdgcn_mfma_f32_16x16x32_bf16(
              afrag[mf], bfrag[nf], acc[mf][nf], 0, 0, 0);
    }
  }
#pragma unroll
  for (int mf = 0; mf < 4; ++mf)
#pragma unroll
    for (int nf = 0; nf < 4; ++nf)
#pragma unroll
      for (int r = 0; r < 4; ++r) {
        int m = m0 + wm * 64 + mf * 16 + q4 * 4 + r;
        int n = n0 + wn * 64 + nf * 16 + l16;
        Y[(size_t)m * 2048 + n] = acc[mf][nf][r];
      }
}

// ------------------------- launch ------------------------------------------
extern "C" void kernel_launch(void* const* d_in, const int* in_sizes, int n_in,
                              void* d_out, int out_size, void* d_ws, size_t ws_size,
                              hipStream_t stream) {
  const float* x = (const float*)d_in[0];
  const float* wqkv = (const float*)d_in[1];
  const float* wproj = (const float*)d_in[2];

  float* y = (float*)d_out;
  float* kout = y + SLICE_;
  float* vout = y + 2 * SLICE_;

  char* w = (char*)d_ws;
  bf16_t* xb = (bf16_t*)w;      w += SLICE_ * 2;
  bf16_t* wqkvb = (bf16_t*)w;   w += (size_t)12582912 * 2;
  bf16_t* wprojb = (bf16_t*)w;  w += (size_t)4194304 * 2;
  bf16_t* qb = (bf16_t*)w;      w += SLICE_ * 2;  // scaled+rope'd q, (B,H,T,hd)
  bf16_t* kb = (bf16_t*)w;      w += SLICE_ * 2;  // rope'd k, (B,H,T,hd)
  bf16_t* vtb = (bf16_t*)w;     w += SLICE_ * 2;  // v, (B,H,hd,T)
  bf16_t* ob = (bf16_t*)w;      w += SLICE_ * 2;  // attn out, (B,T,C)
  float2* tab = (float2*)w;     w += (size_t)131072 * 8;
  (void)ws_size; (void)in_sizes; (void)n_in; (void)out_size;

  static int smem_set = 0;
  if (!smem_set) {
    hipFuncSetAttribute((const void*)k_qkv,
                        hipFuncAttributeMaxDynamicSharedMemorySize, 131072);
    smem_set = 1;
  }

  k_cvt<<<8192, 256, 0, stream>>>((const float4*)x, (bf16x4v*)xb, 2097152);
  k_cvt<<<12288, 256, 0, stream>>>((const float4*)wqkv, (bf16x4v*)wqkvb, 3145728);
  k_cvt<<<4096, 256, 0, stream>>>((const float4*)wproj, (bf16x4v*)wprojb, 1048576);
  k_tab<<<512, 256, 0, stream>>>(tab);

  k_qkv<<<384, 512, 131072, stream>>>(xb, wqkvb, tab, qb, kb, vtb, kout, vout);
  k_attn<<<512, 256, 0, stream>>>(qb, kb, vtb, ob);
  dim3 gp(32, 16);
  k_proj<<<gp, 256, 0, stream>>>(ob, wprojb, y);
}

// Round 2
// 431.500 us; speedup vs baseline: 1.0079x; 1.0079x over previous
//
#include <hip/hip_runtime.h>
#include <math.h>

// ---------------------------------------------------------------------------
// SelfAttention R4: R3's 256x256 8-phase k_qkv with the launch-bounds bug
// fixed: __launch_bounds__(512, 1) (R3's ",2" capped VGPRs at 128 and forced
// accumulator shuttling; LDS=128KiB limits to 1 block/CU anyway).
// k_attn / k_proj / k_cvt / k_tab unchanged.
// ---------------------------------------------------------------------------

typedef __bf16 bf16_t;
typedef __bf16 bf16x8 __attribute__((ext_vector_type(8)));
typedef __bf16 bf16x4v __attribute__((ext_vector_type(4)));
typedef float  f32x4  __attribute__((ext_vector_type(4)));

#define B_  2
#define T_  2048
#define C_  2048
#define SLICE_ ((size_t)B_ * T_ * C_)  // 8388608

__device__ __forceinline__ void glds16(const void* g, void* l) {
  __builtin_amdgcn_global_load_lds(
      (__attribute__((address_space(1))) void*)(void*)(const_cast<void*>(g)),
      (__attribute__((address_space(3))) void*)(l), 16, 0, 0);
}

// ------------------------- f32 -> bf16 pack --------------------------------
__global__ __launch_bounds__(256) void k_cvt(const float4* __restrict__ in,
                                             bf16x4v* __restrict__ out, int n4) {
  int i = blockIdx.x * 256 + threadIdx.x;
  if (i < n4) {
    float4 v = in[i];
    bf16x4v o;
    o[0] = (bf16_t)v.x; o[1] = (bf16_t)v.y; o[2] = (bf16_t)v.z; o[3] = (bf16_t)v.w;
    out[i] = o;
  }
}

// ------------------------- rope cos/sin table ------------------------------
__global__ __launch_bounds__(256) void k_tab(float2* __restrict__ tab) {
  int i = blockIdx.x * 256 + threadIdx.x;  // 131072
  int t = i >> 6, j = i & 63;
  float thf = (float)pow(10000.0, -(double)(2 * j) / 128.0);
  float angf = (float)t * thf;
  double a = (double)angf;
  tab[i] = make_float2((float)cos(a), (float)sin(a));
}

// ------------------------- QKV GEMM + RoPE epilogue ------------------------
// C[m,n] = sum_k X[m,k] W[n,k]; M=4096, N=6144, K=2048.
// 256x256 tile, BK=64, 512 threads (8 waves, 2Mx4N), 128 KiB LDS (2 tiles),
// 8-phase schedule, counted vmcnt(4) at phases 4/8 only.
//
// LDS layout per tile (A or B): [256 rows][64 cols] bf16, 8x16B chunks/row,
// chunk p of row r holds global chunk (p ^ (r&7))  (same swizzle as R2).
// Half-tile = 128 rows = 16 KiB = 2 glds16 per thread.

struct FragA { bf16x8 v[4][2]; };  // 4 mf x 2 ksub
struct FragB { bf16x8 v[2][2]; };  // 2 nf x 2 ksub

__device__ __forceinline__ void stage_half(const bf16_t* __restrict__ g, int k0,
                                           bf16_t* l, int H, int tid) {
  const int wv = tid >> 6;
#pragma unroll
  for (int s = 0; s < 2; ++s) {
    int ci = s * 512 + tid;          // 0..1023 chunk index within half
    int row = ci >> 3;               // 0..127
    glds16(g + (size_t)(H * 128 + row) * 2048 + k0 + (((ci & 7) ^ (row & 7)) << 3),
           l + H * 8192 + (size_t)(s * 512 + wv * 64) * 8);
  }
}

__device__ __forceinline__ void load_afrags(const bf16_t* buf, int ha, int wm,
                                            int l16, int q4, FragA& fa) {
#pragma unroll
  for (int mf = 0; mf < 4; ++mf) {
    const bf16_t* rp = buf + (ha * 128 + wm * 64 + mf * 16 + l16) * 64;
#pragma unroll
    for (int ks = 0; ks < 2; ++ks)
      fa.v[mf][ks] = *(const bf16x8*)(rp + ((((ks << 2) | q4) ^ (l16 & 7)) << 3));
  }
}

__device__ __forceinline__ void load_bfrags(const bf16_t* buf, int hb, int wn,
                                            int l16, int q4, FragB& fb) {
#pragma unroll
  for (int nf = 0; nf < 2; ++nf) {
    const bf16_t* rp = buf + (hb * 128 + wn * 32 + nf * 16 + l16) * 64;
#pragma unroll
    for (int ks = 0; ks < 2; ++ks)
      fb.v[nf][ks] = *(const bf16x8*)(rp + ((((ks << 2) | q4) ^ (l16 & 7)) << 3));
  }
}

template <int HA, int HB>
__device__ __forceinline__ void phase_mfma(const FragA& fa, const FragB& fb,
                                           f32x4 (&acc)[2][4][2][2]) {
  __builtin_amdgcn_s_setprio(1);
#pragma unroll
  for (int ks = 0; ks < 2; ++ks)
#pragma unroll
    for (int mf = 0; mf < 4; ++mf)
#pragma unroll
      for (int nf = 0; nf < 2; ++nf)
        acc[HA][mf][HB][nf] = __builtin_amdgcn_mfma_f32_16x16x32_bf16(
            fa.v[mf][ks], fb.v[nf][ks], acc[HA][mf][HB][nf], 0, 0, 0);
  __builtin_amdgcn_s_setprio(0);
}

#define BARRIER() asm volatile("s_barrier" ::: "memory")
#define VMCNT4()  asm volatile("s_waitcnt vmcnt(4)" ::: "memory")

__global__ __launch_bounds__(512, 1) void k_qkv(
    const bf16_t* __restrict__ X, const bf16_t* __restrict__ W,
    const float2* __restrict__ tab,
    bf16_t* __restrict__ qb, bf16_t* __restrict__ kb, bf16_t* __restrict__ vtb,
    float* __restrict__ kout, float* __restrict__ vout) {
  const int K = 2048;
  extern __shared__ char smem_raw[];   // 131072 B dynamic
  bf16_t* sm = (bf16_t*)smem_raw;
  bf16_t* AE = sm;              // even K-tile A  (16384 elems)
  bf16_t* AO = sm + 16384;      // odd  K-tile A
  bf16_t* BE = sm + 32768;      // even K-tile B
  bf16_t* BO = sm + 49152;      // odd  K-tile B

  const int tid = threadIdx.x;
  const int lane = tid & 63, wv = tid >> 6;
  const int wm = wv >> 2, wn = wv & 3;          // 2M x 4N waves
  const int q4 = lane >> 4, l16 = lane & 15;

  // XCD-aware bijective swizzle over 384 blocks (384 % 8 == 0)
  const int bid = blockIdx.x;
  const int swz = (bid & 7) * 48 + (bid >> 3);
  const int m0 = (swz & 15) * 256;              // 16 m-blocks
  const int n0 = (swz >> 4) * 256;              // 24 n-blocks

  const bf16_t* Ab = X + (size_t)m0 * K;
  const bf16_t* Wb = W + (size_t)n0 * K;

  f32x4 acc[2][4][2][2];
  {
    f32x4 zero4 = {0.f, 0.f, 0.f, 0.f};
#pragma unroll
    for (int ha = 0; ha < 2; ++ha)
#pragma unroll
      for (int mf = 0; mf < 4; ++mf)
#pragma unroll
        for (int hb = 0; hb < 2; ++hb)
#pragma unroll
          for (int nf = 0; nf < 2; ++nf) acc[ha][mf][hb][nf] = zero4;
  }

  // ---- prologue: tile0 (even) fully; tile1 (odd) halves A-h0, B-h1 -------
  stage_half(Ab, 0, AE, 0, tid);
  stage_half(Wb, 0, BE, 0, tid);
  stage_half(Wb, 0, BE, 1, tid);
  stage_half(Ab, 0, AE, 1, tid);
  stage_half(Ab, 64, AO, 0, tid);
  stage_half(Wb, 64, BO, 1, tid);
  VMCNT4();          // 12 issued -> oldest 8 (= whole even tile) landed
  BARRIER();

  // ---- main loop: 16 iters, 2 K-tiles (BK=64) per iter --------------------
  for (int t = 0; t < 16; ++t) {
    const int kO  = t * 128 + 64;            // odd tile of this iter
    const int kE2 = (t * 128 + 128) & 2047;  // next even tile (wraps: harmless)
    const int kO2 = (t * 128 + 192) & 2047;  // next odd tile

    FragA fa; FragB fb;
    // ph1: quadrant (A0,B0) of even tile; stage odd tile B-h0, A-h1
    load_afrags(AE, 0, wm, l16, q4, fa);
    load_bfrags(BE, 0, wn, l16, q4, fb);
    stage_half(Wb, kO, BO, 0, tid);
    stage_half(Ab, kO, AO, 1, tid);
    BARRIER();
    phase_mfma<0, 0>(fa, fb, acc);
    BARRIER();
    // ph2: (A0,B1); fa reused
    load_bfrags(BE, 1, wn, l16, q4, fb);
    BARRIER();
    phase_mfma<0, 1>(fa, fb, acc);
    BARRIER();
    // ph3: (A1,B1); fb reused; stage next-even A-h0 (slot free after ph1)
    load_afrags(AE, 1, wm, l16, q4, fa);
    stage_half(Ab, kE2, AE, 0, tid);
    BARRIER();
    phase_mfma<1, 1>(fa, fb, acc);
    BARRIER();
    // ph4: (A1,B0); stage next-even B-h1 (free after ph2); counted wait
    load_bfrags(BE, 0, wn, l16, q4, fb);
    stage_half(Wb, kE2, BE, 1, tid);
    VMCNT4();   // guarantees everything issued <= ph1 has landed
    BARRIER();
    phase_mfma<1, 0>(fa, fb, acc);
    BARRIER();
    // ph5: (A0,B0) of odd tile; stage next-even B-h0, A-h1 (free after ph4)
    load_afrags(AO, 0, wm, l16, q4, fa);
    load_bfrags(BO, 0, wn, l16, q4, fb);
    stage_half(Wb, kE2, BE, 0, tid);
    stage_half(Ab, kE2, AE, 1, tid);
    BARRIER();
    phase_mfma<0, 0>(fa, fb, acc);
    BARRIER();
    // ph6: (A0,B1)
    load_bfrags(BO, 1, wn, l16, q4, fb);
    BARRIER();
    phase_mfma<0, 1>(fa, fb, acc);
    BARRIER();
    // ph7: (A1,B1); stage next-odd A-h0 (free after ph5)
    load_afrags(AO, 1, wm, l16, q4, fa);
    stage_half(Ab, kO2, AO, 0, tid);
    BARRIER();
    phase_mfma<1, 1>(fa, fb, acc);
    BARRIER();
    // ph8: (A1,B0); stage next-odd B-h1 (free after ph6); counted wait
    load_bfrags(BO, 0, wn, l16, q4, fb);
    stage_half(Wb, kO2, BO, 1, tid);
    VMCNT4();   // guarantees everything issued <= ph5 has landed
    BARRIER();
    phase_mfma<1, 0>(fa, fb, acc);
    BARRIER();
  }

  __syncthreads();  // drains vmcnt(0) + lgkmcnt(0) + barrier; smem reusable

  // ---- epilogue ------------------------------------------------------------
  const int sec = n0 >> 11;                  // 0=q, 1=k, 2=v (block-uniform)
  const int t0 = m0 & 2047, bb = m0 >> 11, h0 = (n0 & 2047) >> 7;

  if (sec < 2) {
    // two passes of 128 rows through LDS (stride 264), RoPE applied
#pragma unroll
    for (int ha = 0; ha < 2; ++ha) {
      if (ha) __syncthreads();
#pragma unroll
      for (int mf = 0; mf < 4; ++mf)
#pragma unroll
        for (int hb = 0; hb < 2; ++hb)
#pragma unroll
          for (int nf = 0; nf < 2; ++nf)
#pragma unroll
            for (int r = 0; r < 4; ++r) {
              int mlr = wm * 64 + mf * 16 + q4 * 4 + r;        // row in half
              int d2  = hb * 128 + wn * 32 + nf * 16 + l16;    // 0..255
              int d   = d2 & 127;
              float val = acc[ha][mf][hb][nf][r];
              float partner = __shfl_xor(val, 1);
              float2 cs = tab[(t0 + ha * 128 + mlr) * 64 + (d >> 1)];
              float rv = (d & 1) ? (val * cs.x + partner * cs.y)
                                 : (val * cs.x - partner * cs.y);
              if (sec == 0) rv *= 0.08838834764831845f;  // fold 1/sqrt(hd)
              else kout[(size_t)(m0 + ha * 128 + mlr) * 2048 +
                        (h0 + hb) * 128 + d] = val;
              sm[mlr * 264 + d2] = (bf16_t)rv;
            }
      __syncthreads();
      bf16_t* dst = (sec == 0 ? qb : kb);
#pragma unroll
      for (int i = 0; i < 8; ++i) {
        int ci = i * 512 + tid;                 // 0..4095
        int mlr = ci >> 5, cc = (ci & 31) * 8;
        int hs = cc >> 7, d = cc & 127;
        *(bf16x8*)(dst +
                   ((size_t)(bb * 16 + h0 + hs) * 2048 + t0 + ha * 128 + mlr) * 128 +
                   d) = *(const bf16x8*)&sm[mlr * 264 + cc];
      }
    }
  } else {
    // v: direct f32 out + 128d x 256t transpose via LDS per head
#pragma unroll
    for (int hb = 0; hb < 2; ++hb) {
      if (hb) __syncthreads();
#pragma unroll
      for (int ha = 0; ha < 2; ++ha)
#pragma unroll
        for (int mf = 0; mf < 4; ++mf)
#pragma unroll
          for (int nf = 0; nf < 2; ++nf)
#pragma unroll
            for (int r = 0; r < 4; ++r) {
              int ml = ha * 128 + wm * 64 + mf * 16 + q4 * 4 + r;  // 0..255
              int d2 = hb * 128 + wn * 32 + nf * 16 + l16;
              int d  = d2 & 127;
              float val = acc[ha][mf][hb][nf][r];
              vout[((size_t)(bb * 16 + h0 + hb) * 2048 + t0 + ml) * 128 + d] = val;
              sm[d * 264 + ml] = (bf16_t)val;   // transpose in LDS
            }
      __syncthreads();
#pragma unroll
      for (int i = 0; i < 8; ++i) {
        int ci = i * 512 + tid;                 // 0..4095
        int dr = ci >> 5, cc = (ci & 31) * 8;
        *(bf16x8*)(vtb +
                   ((size_t)((bb * 16 + h0 + hb) * 128 + dr)) * 2048 + t0 + cc) =
            *(const bf16x8*)&sm[dr * 264 + cc];
      }
    }
  }
}

// ------------------------- flash attention ---------------------------------
// block = (b,h) x 128 queries, 4 waves x 32 queries. KT=64. Q in registers.
// No-max softmax: O_unnorm += exp(s) V; l += sum exp(s); normalize at end.
__global__ __launch_bounds__(256, 2) void k_attn(
    const bf16_t* __restrict__ qb, const bf16_t* __restrict__ kb,
    const bf16_t* __restrict__ vtb, bf16_t* __restrict__ ob) {
  __shared__ alignas(16) bf16_t Ps[128 * 80];   // P tile, stride 80
  __shared__ alignas(16) bf16_t Ks[64 * 128];   // swizzled
  __shared__ alignas(16) bf16_t Vts[128 * 64];  // swizzled, [d][key]

  const int tid = threadIdx.x;
  const int lane = tid & 63, wv = tid >> 6;
  const int q4 = lane >> 4, l16 = lane & 15;
  const int bh = blockIdx.x >> 4;
  const int q0 = (blockIdx.x & 15) * 128;

  const bf16_t* Qg = qb + (size_t)bh * T_ * 128 + (size_t)q0 * 128;
  const bf16_t* Kg = kb + (size_t)bh * T_ * 128;
  const bf16_t* Vg = vtb + (size_t)bh * 128 * T_;

  // Q frags straight from global (one-time, pre-scaled by 1/sqrt(hd))
  bf16x8 qa[2][4];
#pragma unroll
  for (int mf = 0; mf < 2; ++mf)
#pragma unroll
    for (int kf = 0; kf < 4; ++kf)
      qa[mf][kf] = *(const bf16x8*)(Qg + (size_t)(wv * 32 + mf * 16 + l16) * 128 +
                                    kf * 32 + q4 * 8);

  f32x4 zero4 = {0.f, 0.f, 0.f, 0.f};
  float lrow[2][4];
  f32x4 oacc[2][8];
#pragma unroll
  for (int mf = 0; mf < 2; ++mf) {
#pragma unroll
    for (int r = 0; r < 4; ++r) lrow[mf][r] = 0.f;
#pragma unroll
    for (int nf = 0; nf < 8; ++nf) oacc[mf][nf] = zero4;
  }

  for (int key0 = 0; key0 < T_; key0 += 64) {
    __syncthreads();
#pragma unroll
    for (int i = 0; i < 4; ++i) {  // Ks: 64 rows x 16 chunks, swizzled
      int ci = i * 256 + tid;
      glds16(Kg + (size_t)(key0 + (ci >> 4)) * 128 +
                 (((ci & 15) ^ ((ci >> 4) & 7)) << 3),
             &Ks[(i * 256 + wv * 64) * 8]);
    }
#pragma unroll
    for (int i = 0; i < 4; ++i) {  // Vts: 128 rows(d) x 8 chunks, swizzled
      int ci = i * 256 + tid;
      glds16(Vg + (size_t)(ci >> 3) * T_ + key0 +
                 (((ci & 7) ^ ((ci >> 3) & 7)) << 3),
             &Vts[(i * 256 + wv * 64) * 8]);
    }
    __syncthreads();

    // S = Q K^T (pre-scaled)
    f32x4 sacc[2][4];
#pragma unroll
    for (int mf = 0; mf < 2; ++mf)
#pragma unroll
      for (int nf = 0; nf < 4; ++nf) sacc[mf][nf] = zero4;
#pragma unroll
    for (int kf = 0; kf < 4; ++kf) {
      bf16x8 bfrag[4];
#pragma unroll
      for (int nf = 0; nf < 4; ++nf)
        bfrag[nf] = *(const bf16x8*)&Ks[(nf * 16 + l16) * 128 +
                                        ((((kf << 2) | q4) ^ (l16 & 7)) << 3)];
#pragma unroll
      for (int mf = 0; mf < 2; ++mf)
#pragma unroll
        for (int nf = 0; nf < 4; ++nf)
          sacc[mf][nf] = __builtin_amdgcn_mfma_f32_16x16x32_bf16(
              qa[mf][kf], bfrag[nf], sacc[mf][nf], 0, 0, 0);
    }

    // exp + P to LDS; per-lane partial row sums (reduced after key loop)
#pragma unroll
    for (int mf = 0; mf < 2; ++mf) {
#pragma unroll
      for (int r = 0; r < 4; ++r) {
        float p0 = __expf(sacc[mf][0][r]);
        float p1 = __expf(sacc[mf][1][r]);
        float p2 = __expf(sacc[mf][2][r]);
        float p3 = __expf(sacc[mf][3][r]);
        int prow = wv * 32 + mf * 16 + q4 * 4 + r;
        Ps[prow * 80 + 0 + l16]  = (bf16_t)p0;
        Ps[prow * 80 + 16 + l16] = (bf16_t)p1;
        Ps[prow * 80 + 32 + l16] = (bf16_t)p2;
        Ps[prow * 80 + 48 + l16] = (bf16_t)p3;
        lrow[mf][r] += (p0 + p1) + (p2 + p3);
      }
    }

    // O += P V
#pragma unroll
    for (int kf2 = 0; kf2 < 2; ++kf2) {
      bf16x8 pa[2], vb[8];
#pragma unroll
      for (int mf = 0; mf < 2; ++mf)
        pa[mf] = *(const bf16x8*)&Ps[(wv * 32 + mf * 16 + l16) * 80 +
                                     kf2 * 32 + q4 * 8];
#pragma unroll
      for (int nf = 0; nf < 8; ++nf)
        vb[nf] = *(const bf16x8*)&Vts[(nf * 16 + l16) * 64 +
                                      ((((kf2 << 2) | q4) ^ (l16 & 7)) << 3)];
#pragma unroll
      for (int mf = 0; mf < 2; ++mf)
#pragma unroll
        for (int nf = 0; nf < 8; ++nf)
          oacc[mf][nf] = __builtin_amdgcn_mfma_f32_16x16x32_bf16(
              pa[mf], vb[nf], oacc[mf][nf], 0, 0, 0);
    }
  }

  // reduce l across the 16-lane row group, then normalize + store
  const int b = bh >> 4, h = bh & 15;
#pragma unroll
  for (int mf = 0; mf < 2; ++mf) {
#pragma unroll
    for (int r = 0; r < 4; ++r) {
      float l = lrow[mf][r];
      l += __shfl_xor(l, 1);
      l += __shfl_xor(l, 2);
      l += __shfl_xor(l, 4);
      l += __shfl_xor(l, 8);
      float inv = 1.f / l;
      int t = q0 + wv * 32 + mf * 16 + q4 * 4 + r;
      size_t base = ((size_t)b * 2048 + t) * 2048 + h * 128;
#pragma unroll
      for (int nf = 0; nf < 8; ++nf)
        ob[base + nf * 16 + l16] = (bf16_t)(oacc[mf][nf][r] * inv);
    }
  }
}

// ------------------------- projection GEMM ---------------------------------
__global__ __launch_bounds__(256, 2) void k_proj(
    const bf16_t* __restrict__ O, const bf16_t* __restrict__ Wp,
    float* __restrict__ Y) {
  const int K = 2048;
  __shared__ alignas(16) bf16_t As[128 * 64];
  __shared__ alignas(16) bf16_t Bs[128 * 64];
  const int tid = threadIdx.x;
  const int lane = tid & 63, wv = tid >> 6;
  const int wm = wv >> 1, wn = wv & 1;
  const int q4 = lane >> 4, l16 = lane & 15;
  const int m0 = blockIdx.x * 128, n0 = blockIdx.y * 128;

  const bf16_t* Ab = O + (size_t)m0 * K;
  const bf16_t* Wb = Wp + (size_t)n0 * K;

  f32x4 zero4 = {0.f, 0.f, 0.f, 0.f};
  f32x4 acc[4][4];
#pragma unroll
  for (int i = 0; i < 4; ++i)
#pragma unroll
    for (int j = 0; j < 4; ++j) acc[i][j] = zero4;

  for (int k0 = 0; k0 < K; k0 += 64) {
    __syncthreads();
#pragma unroll
    for (int i = 0; i < 4; ++i) {
      int ci = i * 256 + tid;
      glds16(Ab + (size_t)(ci >> 3) * K + k0 + (((ci & 7) ^ ((ci >> 3) & 7)) << 3),
             &As[(i * 256 + wv * 64) * 8]);
    }
#pragma unroll
    for (int i = 0; i < 4; ++i) {
      int ci = i * 256 + tid;
      glds16(Wb + (size_t)(ci >> 3) * K + k0 + (((ci & 7) ^ ((ci >> 3) & 7)) << 3),
             &Bs[(i * 256 + wv * 64) * 8]);
    }
    __syncthreads();
#pragma unroll
    for (int kk = 0; kk < 2; ++kk) {
      bf16x8 afrag[4], bfrag[4];
#pragma unroll
      for (int mf = 0; mf < 4; ++mf)
        afrag[mf] = *(const bf16x8*)&As[(wm * 64 + mf * 16 + l16) * 64 +
                                        ((((kk << 2) | q4) ^ (l16 & 7)) << 3)];
#pragma unroll
      for (int nf = 0; nf < 4; ++nf)
        bfrag[nf] = *(const bf16x8*)&Bs[(wn * 64 + nf * 16 + l16) * 64 +
                                        ((((kk << 2) | q4) ^ (l16 & 7)) << 3)];
#pragma unroll
      for (int mf = 0; mf < 4; ++mf)
#pragma unroll
        for (int nf = 0; nf < 4; ++nf)
          acc[mf][nf] = __builtin_amdgcn_mfma_f32_16x16x32_bf16(
              afrag[mf], bfrag[nf], acc[mf][nf], 0, 0, 0);
    }
  }
#pragma unroll
  for (int mf = 0; mf < 4; ++mf)
#pragma unroll
    for (int nf = 0; nf < 4; ++nf)
#pragma unroll
      for (int r = 0; r < 4; ++r) {
        int m = m0 + wm * 64 + mf * 16 + q4 * 4 + r;
        int n = n0 + wn * 64 + nf * 16 + l16;
        Y[(size_t)m * 2048 + n] = acc[mf][nf][r];
      }
}

// ------------------------- launch ------------------------------------------
extern "C" void kernel_launch(void* const* d_in, const int* in_sizes, int n_in,
                              void* d_out, int out_size, void* d_ws, size_t ws_size,
                              hipStream_t stream) {
  const float* x = (const float*)d_in[0];
  const float* wqkv = (const float*)d_in[1];
  const float* wproj = (const float*)d_in[2];

  float* y = (float*)d_out;
  float* kout = y + SLICE_;
  float* vout = y + 2 * SLICE_;

  char* w = (char*)d_ws;
  bf16_t* xb = (bf16_t*)w;      w += SLICE_ * 2;
  bf16_t* wqkvb = (bf16_t*)w;   w += (size_t)12582912 * 2;
  bf16_t* wprojb = (bf16_t*)w;  w += (size_t)4194304 * 2;
  bf16_t* qb = (bf16_t*)w;      w += SLICE_ * 2;  // scaled+rope'd q, (B,H,T,hd)
  bf16_t* kb = (bf16_t*)w;      w += SLICE_ * 2;  // rope'd k, (B,H,T,hd)
  bf16_t* vtb = (bf16_t*)w;     w += SLICE_ * 2;  // v, (B,H,hd,T)
  bf16_t* ob = (bf16_t*)w;      w += SLICE_ * 2;  // attn out, (B,T,C)
  float2* tab = (float2*)w;     w += (size_t)131072 * 8;
  (void)ws_size; (void)in_sizes; (void)n_in; (void)out_size;

  static int smem_set = 0;
  if (!smem_set) {
    hipFuncSetAttribute((const void*)k_qkv,
                        hipFuncAttributeMaxDynamicSharedMemorySize, 131072);
    smem_set = 1;
  }

  k_cvt<<<8192, 256, 0, stream>>>((const float4*)x, (bf16x4v*)xb, 2097152);
  k_cvt<<<12288, 256, 0, stream>>>((const float4*)wqkv, (bf16x4v*)wqkvb, 3145728);
  k_cvt<<<4096, 256, 0, stream>>>((const float4*)wproj, (bf16x4v*)wprojb, 1048576);
  k_tab<<<512, 256, 0, stream>>>(tab);

  k_qkv<<<384, 512, 131072, stream>>>(xb, wqkvb, tab, qb, kb, vtb, kout, vout);
  k_attn<<<512, 256, 0, stream>>>(qb, kb, vtb, ob);
  dim3 gp(32, 16);
  k_proj<<<gp, 256, 0, stream>>>(ob, wprojb, y);
}